// Round 16
// baseline (200.711 us; speedup 1.0000x reference)
//
#include <hip/hip_runtime.h>
#include <math.h>
#include <stdint.h>

#define B_   2
#define N_   10000
#define E_   160000
#define HID_ 128
#define ED_  32
#define NH_  8
#define HD_  16
#define ROWS_ (B_ * N_)   // 20000

using half2_t = __attribute__((ext_vector_type(2))) _Float16;
using f16x8   = __attribute__((ext_vector_type(8))) _Float16;
using f32x4   = __attribute__((ext_vector_type(4))) float;

__device__ __forceinline__ half2_t f2h2(float a, float b) {
    return __builtin_bit_cast(half2_t, __builtin_amdgcn_cvt_pkrtz(a, b));
}
__device__ __forceinline__ uint32_t pkh2(float a, float b) {
    return __builtin_bit_cast(uint32_t, __builtin_amdgcn_cvt_pkrtz(a, b));
}

// ---------------- CSR build ----------------

__global__ void hist_kernel(const int* __restrict__ ei, int* __restrict__ deg, int E) {
    int e = blockIdx.x * 256 + threadIdx.x;
    if (e < E) atomicAdd(&deg[ei[2 * e + 1]], 1);
}

__global__ __launch_bounds__(256) void scan_kernel(const int* __restrict__ deg,
                                                   int* __restrict__ off, int N) {
    __shared__ int sums[256];
    int t = threadIdx.x;
    int chunk = (N + 255) / 256;
    int s0 = t * chunk, s1 = min(N, s0 + chunk);
    int s = 0;
    for (int i = s0; i < s1; ++i) s += deg[i];
    sums[t] = s;
    __syncthreads();
    #pragma unroll
    for (int d = 1; d < 256; d <<= 1) {
        int v = (t >= d) ? sums[t - d] : 0;
        __syncthreads();
        sums[t] += v;
        __syncthreads();
    }
    if (t == 255) off[N] = sums[255];
    int run = sums[t] - s;
    for (int i = s0; i < s1; ++i) { off[i] = run; run += deg[i]; }
}

__global__ void fill_kernel(const int* __restrict__ ei, const int* __restrict__ off,
                            int* __restrict__ cursor, int* __restrict__ csr,
                            int* __restrict__ srcs, int E) {
    int e = blockIdx.x * 256 + threadIdx.x;
    if (e < E) {
        int2 se = *(const int2*)(ei + 2 * e);   // x=src, y=dst
        int p = atomicAdd(&cursor[se.y], 1);
        int o = off[se.y] + p;
        csr[o] = e;
        srcs[o] = se.x;
    }
}

// ---------------- qkvs MFMA GEMM (R12-proven): [Q | K | V | S] ----------------

#define GM 64
#define LDA 68   // dwords per staged row (64 data + 4 pad)

__global__ __launch_bounds__(256) void qkvs_kernel(
    const float* __restrict__ h,
    const float* __restrict__ Wq, const float* __restrict__ bq,
    const float* __restrict__ Wk, const float* __restrict__ bk,
    const float* __restrict__ Wv, const float* __restrict__ bv,
    const float* __restrict__ Ws, const float* __restrict__ bs,
    const float* __restrict__ ba,
    float* __restrict__ Q, float* __restrict__ KV, float* __restrict__ S)
{
    __shared__ uint32_t As[GM * LDA];
    __shared__ uint32_t Bs[128 * LDA];
    __shared__ float bsm[128];

    int tid = threadIdx.x;
    int lane = tid & 63;
    int wave = tid >> 6;
    int row0 = blockIdx.x * GM;
    int J0 = blockIdx.y * 128;

    if (tid < 128) {
        int J = J0 + tid;
        float v;
        if (J < 128)      v = bq[J];
        else if (J < 256) v = bk[J - 128];
        else if (J < 384) v = bv[J - 256];
        else              v = bs[J - 384] + ba[J - 384];
        bsm[tid] = v;
    }

    for (int f = tid; f < GM * 32; f += 256) {
        int r = f >> 5, c4 = f & 31;
        long row = row0 + r;
        float4 hv = (row < ROWS_) ? *(const float4*)(h + row * HID_ + c4 * 4)
                                  : make_float4(0.f, 0.f, 0.f, 0.f);
        As[r * LDA + c4 * 2]     = pkh2(hv.x, hv.y);
        As[r * LDA + c4 * 2 + 1] = pkh2(hv.z, hv.w);
    }
    for (int f = tid; f < 128 * 32; f += 256) {
        int jr = f >> 5, c4 = f & 31;
        int J = J0 + jr;
        const float* Wp;
        if (J < 128)      Wp = Wq + (long)J * HID_;
        else if (J < 256) Wp = Wk + (long)(J - 128) * HID_;
        else if (J < 384) Wp = Wv + (long)(J - 256) * HID_;
        else              Wp = Ws + (long)(J - 384) * HID_;
        float4 wv = *(const float4*)(Wp + c4 * 4);
        Bs[jr * LDA + c4 * 2]     = pkh2(wv.x, wv.y);
        Bs[jr * LDA + c4 * 2 + 1] = pkh2(wv.z, wv.w);
    }
    __syncthreads();

    f32x4 acc[8];
    #pragma unroll
    for (int nt = 0; nt < 8; ++nt) {
        float c = bsm[nt * 16 + (lane & 15)];
        acc[nt] = (f32x4){ c, c, c, c };
    }

    int ar = wave * 16 + (lane & 15);
    #pragma unroll
    for (int ks = 0; ks < 4; ++ks) {
        f16x8 a = *(const f16x8*)(As + ar * LDA + ks * 16 + (lane >> 4) * 4);
        #pragma unroll
        for (int nt = 0; nt < 8; ++nt) {
            f16x8 b = *(const f16x8*)(Bs + (nt * 16 + (lane & 15)) * LDA + ks * 16 + (lane >> 4) * 4);
            acc[nt] = __builtin_amdgcn_mfma_f32_16x16x32_f16(a, b, acc[nt], 0, 0, 0);
        }
    }

    #pragma unroll
    for (int nt = 0; nt < 8; ++nt) {
        int J = J0 + nt * 16 + (lane & 15);
        long rbase = row0 + wave * 16 + (lane >> 4) * 4;
        #pragma unroll
        for (int r = 0; r < 4; ++r) {
            long row = rbase + r;
            if (row < ROWS_) {
                float v = acc[nt][r];
                if (J < 128)      Q[row * 128 + J] = v;
                else if (J < 256) KV[row * 256 + 2 * (J - 128)] = v;
                else if (J < 384) KV[row * 256 + 2 * (J - 256) + 1] = v;
                else              S[row * 128 + (J - 384)] = v;
            }
        }
    }
}

// ---------------- DPP 16-lane head reduce ----------------

template <int CTRL>
__device__ __forceinline__ float dpp_add(float x) {
    int y = __builtin_amdgcn_mov_dpp(__float_as_int(x), CTRL, 0xF, 0xF, true);
    return x + __int_as_float(y);
}
__device__ __forceinline__ float hsum16(float p) {
    p = dpp_add<0xB1>(p);   // quad_perm xor1
    p = dpp_add<0x4E>(p);   // quad_perm xor2
    p = dpp_add<0x141>(p);  // row_half_mirror
    p = dpp_add<0x140>(p);  // row_mirror
    return p;
}

// ---------------- edge aggregation (R12 + T14 register prefetch) ----------------

#define NPB 4
#define CHUNK 96
#define EAS 20    // dwords per staged ea row (16 data + 4 pad)
#define NPF 6     // float4 prefetch regs per thread: CHUNK*8/128

__global__ __launch_bounds__(128) void node_kernel(
    const float* __restrict__ edge_attr,
    const float* __restrict__ Q, const float* __restrict__ KV,
    const float* __restrict__ We, const float* __restrict__ be,
    const float* __restrict__ attn_vec,
    const int* __restrict__ off, const int* __restrict__ csr,
    const int* __restrict__ srcs,
    float* __restrict__ agg)
{
    int n0 = blockIdx.x * NPB;
    int b  = blockIdx.y;
    int j  = threadIdx.x;           // 0..127
    long bN = (long)b * N_;

    __shared__ int sL[CHUNK];
    __shared__ uint32_t eaL[CHUNK * EAS];

    half2_t we16[16];
    {
        const float4* We4 = (const float4*)(We + (long)j * ED_);
        #pragma unroll
        for (int c = 0; c < 8; ++c) {
            float4 w = We4[c];
            we16[2 * c]     = f2h2(w.x, w.y);
            we16[2 * c + 1] = f2h2(w.z, w.w);
        }
    }
    float bej = be[j];
    float avj = attn_vec[j] * 0.25f;   // fold 1/sqrt(HD)

    float q0 = Q[(bN + n0 + 0) * 128 + j];
    float q1 = Q[(bN + n0 + 1) * 128 + j];
    float q2 = Q[(bN + n0 + 2) * 128 + j];
    float q3 = Q[(bN + n0 + 3) * 128 + j];

    int o0 = off[n0];
    int c1 = off[n0 + 1] - o0, c2 = off[n0 + 2] - o0,
        c3 = off[n0 + 3] - o0, c4_ = off[n0 + 4] - o0;
    int total = c4_;

    const float* eab = edge_attr + (long)b * E_ * ED_;
    const float* KVb = KV + bN * 256;

    float acc0 = 0.f, den0 = 0.f, acc1 = 0.f, den1 = 0.f;
    float acc2 = 0.f, den2 = 0.f, acc3 = 0.f, den3 = 0.f;

    // ---- T14 prefetch: next chunk's srcs + ea into registers ----
    float4 fr0, fr1, fr2, fr3, fr4, fr5;   // named (rule #20: no runtime-indexed arrays)
    int sreg;
    auto prefetch = [&](int tau) {
        int rows = min(total - tau, CHUNK);
        if (j < rows) sreg = srcs[o0 + tau + j];
        #pragma unroll
        for (int u = 0; u < NPF; ++u) {
            int idx = j + u * 128;
            int r = idx >> 3, c = idx & 7;
            float4 v = make_float4(0.f, 0.f, 0.f, 0.f);
            if (r < rows) {
                int e = csr[o0 + tau + r];   // L1-hot
                v = *(const float4*)(eab + (long)e * ED_ + c * 4);
            }
            if (u == 0) fr0 = v; else if (u == 1) fr1 = v; else if (u == 2) fr2 = v;
            else if (u == 3) fr3 = v; else if (u == 4) fr4 = v; else fr5 = v;
        }
    };
    auto stage_from_regs = [&](int rows) {
        if (j < rows) sL[j] = sreg;
        #pragma unroll
        for (int u = 0; u < NPF; ++u) {
            int idx = j + u * 128;
            int r = idx >> 3, c = idx & 7;
            if (r < rows) {
                float4 v = (u == 0) ? fr0 : (u == 1) ? fr1 : (u == 2) ? fr2
                         : (u == 3) ? fr3 : (u == 4) ? fr4 : fr5;
                eaL[r * EAS + 2 * c]     = pkh2(v.x, v.y);
                eaL[r * EAS + 2 * c + 1] = pkh2(v.z, v.w);
            }
        }
    };

    auto edge_body = [&](int i, float qg, float& accg, float& deng) {
        int s = sL[i];
        float2 kv = *(const float2*)(KVb + (long)s * 256 + 2 * j);
        float eja = bej, ejb = 0.f;
        const half2_t* ea = (const half2_t*)(eaL + i * EAS);
        #pragma unroll
        for (int c = 0; c < 8; ++c) {
            eja = __builtin_amdgcn_fdot2(we16[c], ea[c], eja, false);
            ejb = __builtin_amdgcn_fdot2(we16[c + 8], ea[c + 8], ejb, false);
        }
        float ej = eja + ejb;
        float y = qg + kv.x + ej;
        float t = 1.f - 2.f * __builtin_amdgcn_rcpf(__expf(2.f * y) + 1.f);
        float p = hsum16(t * avj);
        float ex = __expf(p);
        deng += ex;
        accg += ex * (kv.y + ej);
    };

    auto range_loop = [&](int lo, int hi, float qg, float& accg, float& deng) {
        int i = lo;
        for (; i + 3 < hi; i += 4) {
            edge_body(i, qg, accg, deng);
            edge_body(i + 1, qg, accg, deng);
            edge_body(i + 2, qg, accg, deng);
            edge_body(i + 3, qg, accg, deng);
        }
        for (; i < hi; ++i) edge_body(i, qg, accg, deng);
    };

    prefetch(0);
    for (int tau = 0; tau < total; tau += CHUNK) {
        int rows = min(total - tau, CHUNK);
        __syncthreads();            // eaL/sL free (readers done)
        stage_from_regs(rows);
        __syncthreads();            // staging visible
        if (tau + CHUNK < total)
            prefetch(tau + CHUNK);  // loads fly under the edge loop below

        range_loop(max(0 - tau, 0),   min(c1 - tau, rows), q0, acc0, den0);
        range_loop(max(c1 - tau, 0),  min(c2 - tau, rows), q1, acc1, den1);
        range_loop(max(c2 - tau, 0),  min(c3 - tau, rows), q2, acc2, den2);
        range_loop(max(c3 - tau, 0),  min(c4_ - tau, rows), q3, acc3, den3);
    }

    agg[(bN + n0 + 0) * 128 + j] = (c1 > 0)   ? acc0 * __builtin_amdgcn_rcpf(den0) : 0.f;
    agg[(bN + n0 + 1) * 128 + j] = (c2 > c1)  ? acc1 * __builtin_amdgcn_rcpf(den1) : 0.f;
    agg[(bN + n0 + 2) * 128 + j] = (c3 > c2)  ? acc2 * __builtin_amdgcn_rcpf(den2) : 0.f;
    agg[(bN + n0 + 3) * 128 + j] = (c4_ > c3) ? acc3 * __builtin_amdgcn_rcpf(den3) : 0.f;
}

// ---------------- wa + gelu + residual + LayerNorm, fused (R12-proven) ----------------

__global__ __launch_bounds__(256) void wa_ln_kernel(
    const float* __restrict__ X,   // agg
    const float* __restrict__ Wa,
    const float* __restrict__ S, const float* __restrict__ h,
    const float* __restrict__ ln_g, const float* __restrict__ ln_b,
    float* __restrict__ out)
{
    __shared__ uint32_t As[GM * LDA];
    __shared__ uint32_t Bs[128 * LDA];

    int tid = threadIdx.x;
    int lane = tid & 63;
    int wave = tid >> 6;
    int row0 = blockIdx.x * GM;

    for (int f = tid; f < GM * 32; f += 256) {
        int r = f >> 5, c4 = f & 31;
        long row = row0 + r;
        float4 hv = (row < ROWS_) ? *(const float4*)(X + row * HID_ + c4 * 4)
                                  : make_float4(0.f, 0.f, 0.f, 0.f);
        As[r * LDA + c4 * 2]     = pkh2(hv.x, hv.y);
        As[r * LDA + c4 * 2 + 1] = pkh2(hv.z, hv.w);
    }
    for (int f = tid; f < 128 * 32; f += 256) {
        int jr = f >> 5, c4 = f & 31;
        float4 wv = *(const float4*)(Wa + (long)jr * HID_ + c4 * 4);
        Bs[jr * LDA + c4 * 2]     = pkh2(wv.x, wv.y);
        Bs[jr * LDA + c4 * 2 + 1] = pkh2(wv.z, wv.w);
    }
    __syncthreads();

    f32x4 acc[8];
    #pragma unroll
    for (int nt = 0; nt < 8; ++nt) acc[nt] = (f32x4){ 0.f, 0.f, 0.f, 0.f };

    int lq = lane & 15;
    int ar = wave * 16 + lq;
    #pragma unroll
    for (int ks = 0; ks < 4; ++ks) {
        f16x8 a = *(const f16x8*)(As + ar * LDA + ks * 16 + (lane >> 4) * 4);
        #pragma unroll
        for (int nt = 0; nt < 8; ++nt) {
            f16x8 b = *(const f16x8*)(Bs + (nt * 16 + lq) * LDA + ks * 16 + (lane >> 4) * 4);
            acc[nt] = __builtin_amdgcn_mfma_f32_16x16x32_f16(a, b, acc[nt], 0, 0, 0);
        }
    }

    float gJ[8], bJ[8];
    #pragma unroll
    for (int nt = 0; nt < 8; ++nt) {
        int J = nt * 16 + lq;
        gJ[nt] = ln_g[J];
        bJ[nt] = ln_b[J];
    }
    long rbase = row0 + wave * 16 + (lane >> 4) * 4;
    #pragma unroll
    for (int r = 0; r < 4; ++r) {
        long row = rbase + r;
        if (row < ROWS_) {
            float xv[8];
            float sum = 0.f, sum2 = 0.f;
            #pragma unroll
            for (int nt = 0; nt < 8; ++nt) {
                int J = nt * 16 + lq;
                float upd = acc[nt][r] + S[row * 128 + J];
                float ge = 0.5f * upd * (1.f + erff(upd * 0.70710678118654752f));
                float x = h[row * 128 + J] + ge;
                xv[nt] = x;
                sum += x;
                sum2 += x * x;
            }
            sum = hsum16(sum);
            sum2 = hsum16(sum2);
            float mu = sum * (1.f / 128.f);
            float var = sum2 * (1.f / 128.f) - mu * mu;
            float rs = rsqrtf(var + 1e-5f);
            #pragma unroll
            for (int nt = 0; nt < 8; ++nt)
                out[row * 128 + nt * 16 + lq] = (xv[nt] - mu) * rs * gJ[nt] + bJ[nt];
        }
    }
}

// ---------------- launch ----------------

extern "C" void kernel_launch(void* const* d_in, const int* in_sizes, int n_in,
                              void* d_out, int out_size, void* d_ws, size_t ws_size,
                              hipStream_t stream) {
    const float* h         = (const float*)d_in[0];
    const float* edge_attr = (const float*)d_in[1];
    const int*   ei        = (const int*)  d_in[2];
    const float* Wq = (const float*)d_in[3];
    const float* bq = (const float*)d_in[4];
    const float* Wk = (const float*)d_in[5];
    const float* bk = (const float*)d_in[6];
    const float* Wv = (const float*)d_in[7];
    const float* bv = (const float*)d_in[8];
    const float* We = (const float*)d_in[9];
    const float* be = (const float*)d_in[10];
    const float* attn_vec = (const float*)d_in[11];
    const float* Ws = (const float*)d_in[12];
    const float* bs = (const float*)d_in[13];
    const float* Wa = (const float*)d_in[14];
    const float* ba = (const float*)d_in[15];
    const float* ln_g = (const float*)d_in[16];
    const float* ln_b = (const float*)d_in[17];
    float* out = (float*)d_out;

    size_t p = 0;
    auto alloc = [&](size_t bytes) { size_t r = p; p += (bytes + 255) & ~(size_t)255; return r; };
    char* ws = (char*)d_ws;
    float* Q    = (float*)(ws + alloc((size_t)ROWS_ * 128 * 4));
    float* KV   = (float*)(ws + alloc((size_t)ROWS_ * 256 * 4));
    float* S    = (float*)(ws + alloc((size_t)ROWS_ * 128 * 4));
    float* agg  = (float*)(ws + alloc((size_t)ROWS_ * 128 * 4));
    int* dc     = (int*)(ws + alloc((size_t)2 * N_ * 4));   // deg | cursor
    int* off    = (int*)(ws + alloc((size_t)(N_ + 1) * 4));
    int* csr    = (int*)(ws + alloc((size_t)E_ * 4));
    int* srcs   = (int*)(ws + alloc((size_t)E_ * 4));
    int* deg = dc;
    int* cursor = dc + N_;
    (void)ws_size;

    hipMemsetAsync(dc, 0, (size_t)2 * N_ * 4, stream);
    hist_kernel<<<(E_ + 255) / 256, 256, 0, stream>>>(ei, deg, E_);
    scan_kernel<<<1, 256, 0, stream>>>(deg, off, N_);
    fill_kernel<<<(E_ + 255) / 256, 256, 0, stream>>>(ei, off, cursor, csr, srcs, E_);

    dim3 ggrid((ROWS_ + GM - 1) / GM, 4);
    qkvs_kernel<<<ggrid, 256, 0, stream>>>(h, Wq, bq, Wk, bk, Wv, bv, Ws, bs, ba,
                                           Q, KV, S);

    dim3 grid(N_ / NPB, B_);
    node_kernel<<<grid, 128, 0, stream>>>(edge_attr, Q, KV, We, be, attn_vec,
                                          off, csr, srcs, agg);

    wa_ln_kernel<<<(ROWS_ + GM - 1) / GM, 256, 0, stream>>>(agg, Wa, S, h,
                                                            ln_g, ln_b, out);
}

// Round 17
// 177.207 us; speedup vs baseline: 1.1326x; 1.1326x over previous
//
#include <hip/hip_runtime.h>
#include <math.h>
#include <stdint.h>

#define B_   2
#define N_   10000
#define E_   160000
#define HID_ 128
#define ED_  32
#define NH_  8
#define HD_  16
#define ROWS_ (B_ * N_)   // 20000

using half2_t = __attribute__((ext_vector_type(2))) _Float16;
using f16x8   = __attribute__((ext_vector_type(8))) _Float16;
using f32x4   = __attribute__((ext_vector_type(4))) float;

__device__ __forceinline__ half2_t f2h2(float a, float b) {
    return __builtin_bit_cast(half2_t, __builtin_amdgcn_cvt_pkrtz(a, b));
}
__device__ __forceinline__ uint32_t pkh2(float a, float b) {
    return __builtin_bit_cast(uint32_t, __builtin_amdgcn_cvt_pkrtz(a, b));
}

// ---------------- CSR build ----------------

__global__ void hist_kernel(const int* __restrict__ ei, int* __restrict__ deg, int E) {
    int e = blockIdx.x * 256 + threadIdx.x;
    if (e < E) atomicAdd(&deg[ei[2 * e + 1]], 1);
}

// parallel block scan (Hillis-Steele over 256 per-thread partial sums)
__global__ __launch_bounds__(256) void scan_kernel(const int* __restrict__ deg,
                                                   int* __restrict__ off, int N) {
    __shared__ int sums[256];
    int t = threadIdx.x;
    int chunk = (N + 255) / 256;
    int s0 = t * chunk, s1 = min(N, s0 + chunk);
    int s = 0;
    for (int i = s0; i < s1; ++i) s += deg[i];
    sums[t] = s;
    __syncthreads();
    #pragma unroll
    for (int d = 1; d < 256; d <<= 1) {
        int v = (t >= d) ? sums[t - d] : 0;
        __syncthreads();
        sums[t] += v;
        __syncthreads();
    }
    if (t == 255) off[N] = sums[255];
    int run = sums[t] - s;
    for (int i = s0; i < s1; ++i) { off[i] = run; run += deg[i]; }
}

// fill: also emit srcs[] (src node id in CSR order) — same 8B ei read
__global__ void fill_kernel(const int* __restrict__ ei, const int* __restrict__ off,
                            int* __restrict__ cursor, int* __restrict__ csr,
                            int* __restrict__ srcs, int E) {
    int e = blockIdx.x * 256 + threadIdx.x;
    if (e < E) {
        int2 se = *(const int2*)(ei + 2 * e);   // x=src, y=dst
        int p = atomicAdd(&cursor[se.y], 1);
        int o = off[se.y] + p;
        csr[o] = e;
        srcs[o] = se.x;
    }
}

// ---------------- qkvs MFMA GEMM (R9-proven): [Q | K | V | S] ----------------
// Q f32 [row][128]; KV f32 interleaved [row][256] (2j=K_j, 2j+1=V_j); S f32 (incl. bs+ba).

#define GM 64
#define LDA 68   // dwords per staged row (64 data + 4 pad)

__global__ __launch_bounds__(256) void qkvs_kernel(
    const float* __restrict__ h,
    const float* __restrict__ Wq, const float* __restrict__ bq,
    const float* __restrict__ Wk, const float* __restrict__ bk,
    const float* __restrict__ Wv, const float* __restrict__ bv,
    const float* __restrict__ Ws, const float* __restrict__ bs,
    const float* __restrict__ ba,
    float* __restrict__ Q, float* __restrict__ KV, float* __restrict__ S)
{
    __shared__ uint32_t As[GM * LDA];
    __shared__ uint32_t Bs[128 * LDA];
    __shared__ float bsm[128];

    int tid = threadIdx.x;
    int lane = tid & 63;
    int wave = tid >> 6;
    int row0 = blockIdx.x * GM;
    int J0 = blockIdx.y * 128;

    if (tid < 128) {
        int J = J0 + tid;
        float v;
        if (J < 128)      v = bq[J];
        else if (J < 256) v = bk[J - 128];
        else if (J < 384) v = bv[J - 256];
        else              v = bs[J - 384] + ba[J - 384];
        bsm[tid] = v;
    }

    for (int f = tid; f < GM * 32; f += 256) {
        int r = f >> 5, c4 = f & 31;
        long row = row0 + r;
        float4 hv = (row < ROWS_) ? *(const float4*)(h + row * HID_ + c4 * 4)
                                  : make_float4(0.f, 0.f, 0.f, 0.f);
        As[r * LDA + c4 * 2]     = pkh2(hv.x, hv.y);
        As[r * LDA + c4 * 2 + 1] = pkh2(hv.z, hv.w);
    }
    for (int f = tid; f < 128 * 32; f += 256) {
        int jr = f >> 5, c4 = f & 31;
        int J = J0 + jr;
        const float* Wp;
        if (J < 128)      Wp = Wq + (long)J * HID_;
        else if (J < 256) Wp = Wk + (long)(J - 128) * HID_;
        else if (J < 384) Wp = Wv + (long)(J - 256) * HID_;
        else              Wp = Ws + (long)(J - 384) * HID_;
        float4 wv = *(const float4*)(Wp + c4 * 4);
        Bs[jr * LDA + c4 * 2]     = pkh2(wv.x, wv.y);
        Bs[jr * LDA + c4 * 2 + 1] = pkh2(wv.z, wv.w);
    }
    __syncthreads();

    f32x4 acc[8];
    #pragma unroll
    for (int nt = 0; nt < 8; ++nt) {
        float c = bsm[nt * 16 + (lane & 15)];
        acc[nt] = (f32x4){ c, c, c, c };
    }

    int ar = wave * 16 + (lane & 15);
    #pragma unroll
    for (int ks = 0; ks < 4; ++ks) {
        f16x8 a = *(const f16x8*)(As + ar * LDA + ks * 16 + (lane >> 4) * 4);
        #pragma unroll
        for (int nt = 0; nt < 8; ++nt) {
            f16x8 b = *(const f16x8*)(Bs + (nt * 16 + (lane & 15)) * LDA + ks * 16 + (lane >> 4) * 4);
            acc[nt] = __builtin_amdgcn_mfma_f32_16x16x32_f16(a, b, acc[nt], 0, 0, 0);
        }
    }

    #pragma unroll
    for (int nt = 0; nt < 8; ++nt) {
        int J = J0 + nt * 16 + (lane & 15);
        long rbase = row0 + wave * 16 + (lane >> 4) * 4;
        #pragma unroll
        for (int r = 0; r < 4; ++r) {
            long row = rbase + r;
            if (row < ROWS_) {
                float v = acc[nt][r];
                if (J < 128)      Q[row * 128 + J] = v;
                else if (J < 256) KV[row * 256 + 2 * (J - 128)] = v;
                else if (J < 384) KV[row * 256 + 2 * (J - 256) + 1] = v;
                else              S[row * 128 + (J - 384)] = v;
            }
        }
    }
}

// ---------------- DPP 16-lane head reduce ----------------

template <int CTRL>
__device__ __forceinline__ float dpp_add(float x) {
    int y = __builtin_amdgcn_mov_dpp(__float_as_int(x), CTRL, 0xF, 0xF, true);
    return x + __int_as_float(y);
}
__device__ __forceinline__ float hsum16(float p) {
    p = dpp_add<0xB1>(p);   // quad_perm xor1
    p = dpp_add<0x4E>(p);   // quad_perm xor2
    p = dpp_add<0x141>(p);  // row_half_mirror
    p = dpp_add<0x140>(p);  // row_mirror
    return p;
}

// ---------------- edge aggregation (R9-proven): 4 nodes/block, 128 threads ----------------

#define NPB 4
#define CHUNK 96
#define EAS 20   // dwords per staged ea row (16 data + 4 pad)

__global__ __launch_bounds__(128) void node_kernel(
    const float* __restrict__ edge_attr,
    const float* __restrict__ Q, const float* __restrict__ KV,
    const float* __restrict__ We, const float* __restrict__ be,
    const float* __restrict__ attn_vec,
    const int* __restrict__ off, const int* __restrict__ csr,
    const int* __restrict__ srcs,
    float* __restrict__ agg)
{
    int n0 = blockIdx.x * NPB;
    int b  = blockIdx.y;
    int j  = threadIdx.x;           // 0..127
    long bN = (long)b * N_;

    __shared__ int sL[CHUNK];
    __shared__ uint32_t eaL[CHUNK * EAS];

    half2_t we16[16];
    {
        const float4* We4 = (const float4*)(We + (long)j * ED_);
        #pragma unroll
        for (int c = 0; c < 8; ++c) {
            float4 w = We4[c];
            we16[2 * c]     = f2h2(w.x, w.y);
            we16[2 * c + 1] = f2h2(w.z, w.w);
        }
    }
    float bej = be[j];
    float avj = attn_vec[j] * 0.25f;   // fold 1/sqrt(HD)

    float q0 = Q[(bN + n0 + 0) * 128 + j];
    float q1 = Q[(bN + n0 + 1) * 128 + j];
    float q2 = Q[(bN + n0 + 2) * 128 + j];
    float q3 = Q[(bN + n0 + 3) * 128 + j];

    int o0 = off[n0];
    int c1 = off[n0 + 1] - o0, c2 = off[n0 + 2] - o0,
        c3 = off[n0 + 3] - o0, c4_ = off[n0 + 4] - o0;
    int total = c4_;

    const float* eab = edge_attr + (long)b * E_ * ED_;
    const float* KVb = KV + bN * 256;

    float acc0 = 0.f, den0 = 0.f, acc1 = 0.f, den1 = 0.f;
    float acc2 = 0.f, den2 = 0.f, acc3 = 0.f, den3 = 0.f;

    auto edge_body = [&](int i, float qg, float& accg, float& deng) {
        int s = sL[i];
        float2 kv = *(const float2*)(KVb + (long)s * 256 + 2 * j);
        float eja = bej, ejb = 0.f;
        const half2_t* ea = (const half2_t*)(eaL + i * EAS);
        #pragma unroll
        for (int c = 0; c < 8; ++c) {
            eja = __builtin_amdgcn_fdot2(we16[c], ea[c], eja, false);
            ejb = __builtin_amdgcn_fdot2(we16[c + 8], ea[c + 8], ejb, false);
        }
        float ej = eja + ejb;
        float y = qg + kv.x + ej;
        float t = 1.f - 2.f * __builtin_amdgcn_rcpf(__expf(2.f * y) + 1.f);
        float p = hsum16(t * avj);
        float ex = __expf(p);
        deng += ex;
        accg += ex * (kv.y + ej);
    };

    auto range_loop = [&](int lo, int hi, float qg, float& accg, float& deng) {
        int i = lo;
        for (; i + 3 < hi; i += 4) {
            edge_body(i, qg, accg, deng);
            edge_body(i + 1, qg, accg, deng);
            edge_body(i + 2, qg, accg, deng);
            edge_body(i + 3, qg, accg, deng);
        }
        for (; i < hi; ++i) edge_body(i, qg, accg, deng);
    };

    for (int tau = 0; tau < total; tau += CHUNK) {
        int rows = min(total - tau, CHUNK);
        __syncthreads();
        for (int t = j; t < rows; t += 128)
            sL[t] = srcs[o0 + tau + t];          // coalesced (no ei gather)
        for (int idx = j; idx < rows * 8; idx += 128) {
            int r = idx >> 3, c = idx & 7;
            int e = csr[o0 + tau + r];           // L1-hot re-read
            float4 f = *(const float4*)(eab + (long)e * ED_ + c * 4);
            eaL[r * EAS + 2 * c]     = pkh2(f.x, f.y);
            eaL[r * EAS + 2 * c + 1] = pkh2(f.z, f.w);
        }
        __syncthreads();

        range_loop(max(0 - tau, 0),   min(c1 - tau, rows), q0, acc0, den0);
        range_loop(max(c1 - tau, 0),  min(c2 - tau, rows), q1, acc1, den1);
        range_loop(max(c2 - tau, 0),  min(c3 - tau, rows), q2, acc2, den2);
        range_loop(max(c3 - tau, 0),  min(c4_ - tau, rows), q3, acc3, den3);
    }

    agg[(bN + n0 + 0) * 128 + j] = (c1 > 0)   ? acc0 * __builtin_amdgcn_rcpf(den0) : 0.f;
    agg[(bN + n0 + 1) * 128 + j] = (c2 > c1)  ? acc1 * __builtin_amdgcn_rcpf(den1) : 0.f;
    agg[(bN + n0 + 2) * 128 + j] = (c3 > c2)  ? acc2 * __builtin_amdgcn_rcpf(den2) : 0.f;
    agg[(bN + n0 + 3) * 128 + j] = (c4_ > c3) ? acc3 * __builtin_amdgcn_rcpf(den3) : 0.f;
}

// ---------------- wa + gelu + residual + LayerNorm, fused ----------------
// A = agg @ Wa^T; upd = A + S; x = h + gelu(upd); out = LN(x)*g + b.
// Row-reduce for LN via hsum16 over the 16-lane C-fragment col groups.

__global__ __launch_bounds__(256) void wa_ln_kernel(
    const float* __restrict__ X,   // agg
    const float* __restrict__ Wa,
    const float* __restrict__ S, const float* __restrict__ h,
    const float* __restrict__ ln_g, const float* __restrict__ ln_b,
    float* __restrict__ out)
{
    __shared__ uint32_t As[GM * LDA];
    __shared__ uint32_t Bs[128 * LDA];

    int tid = threadIdx.x;
    int lane = tid & 63;
    int wave = tid >> 6;
    int row0 = blockIdx.x * GM;

    for (int f = tid; f < GM * 32; f += 256) {
        int r = f >> 5, c4 = f & 31;
        long row = row0 + r;
        float4 hv = (row < ROWS_) ? *(const float4*)(X + row * HID_ + c4 * 4)
                                  : make_float4(0.f, 0.f, 0.f, 0.f);
        As[r * LDA + c4 * 2]     = pkh2(hv.x, hv.y);
        As[r * LDA + c4 * 2 + 1] = pkh2(hv.z, hv.w);
    }
    for (int f = tid; f < 128 * 32; f += 256) {
        int jr = f >> 5, c4 = f & 31;
        float4 wv = *(const float4*)(Wa + (long)jr * HID_ + c4 * 4);
        Bs[jr * LDA + c4 * 2]     = pkh2(wv.x, wv.y);
        Bs[jr * LDA + c4 * 2 + 1] = pkh2(wv.z, wv.w);
    }
    __syncthreads();

    f32x4 acc[8];
    #pragma unroll
    for (int nt = 0; nt < 8; ++nt) acc[nt] = (f32x4){ 0.f, 0.f, 0.f, 0.f };

    int lq = lane & 15;
    int ar = wave * 16 + lq;
    #pragma unroll
    for (int ks = 0; ks < 4; ++ks) {
        f16x8 a = *(const f16x8*)(As + ar * LDA + ks * 16 + (lane >> 4) * 4);
        #pragma unroll
        for (int nt = 0; nt < 8; ++nt) {
            f16x8 b = *(const f16x8*)(Bs + (nt * 16 + lq) * LDA + ks * 16 + (lane >> 4) * 4);
            acc[nt] = __builtin_amdgcn_mfma_f32_16x16x32_f16(a, b, acc[nt], 0, 0, 0);
        }
    }

    // fused epilogue
    float gJ[8], bJ[8];
    #pragma unroll
    for (int nt = 0; nt < 8; ++nt) {
        int J = nt * 16 + lq;
        gJ[nt] = ln_g[J];
        bJ[nt] = ln_b[J];
    }
    long rbase = row0 + wave * 16 + (lane >> 4) * 4;
    #pragma unroll
    for (int r = 0; r < 4; ++r) {
        long row = rbase + r;
        if (row < ROWS_) {
            float xv[8];
            float sum = 0.f, sum2 = 0.f;
            #pragma unroll
            for (int nt = 0; nt < 8; ++nt) {
                int J = nt * 16 + lq;
                float upd = acc[nt][r] + S[row * 128 + J];
                float ge = 0.5f * upd * (1.f + erff(upd * 0.70710678118654752f));
                float x = h[row * 128 + J] + ge;
                xv[nt] = x;
                sum += x;
                sum2 += x * x;
            }
            sum = hsum16(sum);
            sum2 = hsum16(sum2);
            float mu = sum * (1.f / 128.f);
            float var = sum2 * (1.f / 128.f) - mu * mu;
            float rs = rsqrtf(var + 1e-5f);
            #pragma unroll
            for (int nt = 0; nt < 8; ++nt)
                out[row * 128 + nt * 16 + lq] = (xv[nt] - mu) * rs * gJ[nt] + bJ[nt];
        }
    }
}

// ---------------- launch ----------------

extern "C" void kernel_launch(void* const* d_in, const int* in_sizes, int n_in,
                              void* d_out, int out_size, void* d_ws, size_t ws_size,
                              hipStream_t stream) {
    const float* h         = (const float*)d_in[0];
    const float* edge_attr = (const float*)d_in[1];
    const int*   ei        = (const int*)  d_in[2];
    const float* Wq = (const float*)d_in[3];
    const float* bq = (const float*)d_in[4];
    const float* Wk = (const float*)d_in[5];
    const float* bk = (const float*)d_in[6];
    const float* Wv = (const float*)d_in[7];
    const float* bv = (const float*)d_in[8];
    const float* We = (const float*)d_in[9];
    const float* be = (const float*)d_in[10];
    const float* attn_vec = (const float*)d_in[11];
    const float* Ws = (const float*)d_in[12];
    const float* bs = (const float*)d_in[13];
    const float* Wa = (const float*)d_in[14];
    const float* ba = (const float*)d_in[15];
    const float* ln_g = (const float*)d_in[16];
    const float* ln_b = (const float*)d_in[17];
    float* out = (float*)d_out;

    size_t p = 0;
    auto alloc = [&](size_t bytes) { size_t r = p; p += (bytes + 255) & ~(size_t)255; return r; };
    char* ws = (char*)d_ws;
    float* Q    = (float*)(ws + alloc((size_t)ROWS_ * 128 * 4));
    float* KV   = (float*)(ws + alloc((size_t)ROWS_ * 256 * 4));
    float* S    = (float*)(ws + alloc((size_t)ROWS_ * 128 * 4));
    float* agg  = (float*)(ws + alloc((size_t)ROWS_ * 128 * 4));
    int* dc     = (int*)(ws + alloc((size_t)2 * N_ * 4));   // deg | cursor, contiguous
    int* off    = (int*)(ws + alloc((size_t)(N_ + 1) * 4));
    int* csr    = (int*)(ws + alloc((size_t)E_ * 4));
    int* srcs   = (int*)(ws + alloc((size_t)E_ * 4));
    int* deg = dc;
    int* cursor = dc + N_;
    (void)ws_size;

    hipMemsetAsync(dc, 0, (size_t)2 * N_ * 4, stream);
    hist_kernel<<<(E_ + 255) / 256, 256, 0, stream>>>(ei, deg, E_);
    scan_kernel<<<1, 256, 0, stream>>>(deg, off, N_);
    fill_kernel<<<(E_ + 255) / 256, 256, 0, stream>>>(ei, off, cursor, csr, srcs, E_);

    dim3 ggrid((ROWS_ + GM - 1) / GM, 4);
    qkvs_kernel<<<ggrid, 256, 0, stream>>>(h, Wq, bq, Wk, bk, Wv, bv, Ws, bs, ba,
                                           Q, KV, S);

    dim3 grid(N_ / NPB, B_);
    node_kernel<<<grid, 128, 0, stream>>>(edge_attr, Q, KV, We, be, attn_vec,
                                          off, csr, srcs, agg);

    wa_ln_kernel<<<(ROWS_ + GM - 1) / GM, 256, 0, stream>>>(agg, Wa, S, h,
                                                            ln_g, ln_b, out);
}